// Round 5
// baseline (346.444 us; speedup 1.0000x reference)
//
#include <hip/hip_runtime.h>

#define N_NODES 50000
#define E_EDGES 800000
#define IN_DIM 256
#define H_HEADS 4
#define F_OUT 64
#define EF_DIM 64
#define NT_TYPES 8
#define SLOPE 0.2f
#define HF 256  /* H*F */

typedef __attribute__((ext_vector_type(8))) short short8;
typedef __attribute__((ext_vector_type(4))) float f32x4;
typedef unsigned short ushort_t;
typedef unsigned long long u64;

// workspace layout (float element offsets)
#define FEATBF_OFF 0          /* N*HF bf16 = 6.4M floats */
#define EL_OFF   6400000
#define ER_OFF   6600000
#define EE_OFF   6800000
#define BT_OFF   6800064      /* 256x256 bf16 = 32768 floats */
#define INT_OFF  6832832
// int offsets within int region (no atomics -> no zeroed arrays needed)
#define CNT_IOFF     0        /* cnt16 ushort[16][50000] = 400,000 ints; becomes within-node prefix */
#define RANK_IOFF    400000   /* rank16 ushort[800,000] = 400,000 ints */
#define DEG_IOFF     800000   /* int[50,000] */
#define RL_IOFF      850000   /* int[50,000] */
#define BO_IOFF      900000   /* int[256] */
#define PK_IOFF      900256   /* u64[800,000] (8B aligned: even int offset) */

#define NBLK_GEMM 782         /* ceil(50000/64) */
#define NBLK_E4   782         /* ceil(800000/4/256) */
#define NCHUNK    196         /* ceil(50000/256) */

// khist geometry: 16 edge-partitions x 4 node-partitions
#define BE 16
#define BN 4
#define EPB 50000             /* edges per partition (800000/16) */
#define NPB 12500             /* nodes per partition (50000/4) */
#define NBLK_KHIST (BE * BN)  /* 64 */

__device__ __forceinline__ ushort_t f2bf(float f) {
    unsigned u = __float_as_uint(f);
    u += 0x7fffu + ((u >> 16) & 1u);   // round-nearest-even
    return (ushort_t)(u >> 16);
}
__device__ __forceinline__ float bf2f(ushort_t b) {
    return __uint_as_float(((unsigned)b) << 16);
}

// ======================= K1: ee + cast_w (tiny) =======================
__global__ __launch_bounds__(256) void k1_prep(
    const float* __restrict__ edge_emb, const float* __restrict__ fc_e_w,
    const float* __restrict__ attn_e, const float* __restrict__ fc_w,
    float* __restrict__ ee, ushort_t* __restrict__ Bt)
{
    const int b = blockIdx.x;
    if (b == 0) {
        const int c = threadIdx.x;
        const float ae = attn_e[c];
        const int lane = c & 63, h = c >> 6;
        for (int ty = 0; ty < NT_TYPES; ty++) {
            float v = 0.f;
            #pragma unroll 8
            for (int k = 0; k < EF_DIM; k++)
                v = fmaf(edge_emb[ty * EF_DIM + k], fc_e_w[k * (H_HEADS * EF_DIM) + c], v);
            float contrib = v * ae;
            #pragma unroll
            for (int m = 32; m >= 1; m >>= 1) contrib += __shfl_xor(contrib, m);
            if (lane == 0) ee[ty * H_HEADS + h] = contrib;
        }
    } else {
        const int k = b - 1, c = threadIdx.x;
        Bt[(size_t)c * 256 + k] = f2bf(fc_w[(size_t)k * 256 + c]);
    }
}

// ======================= GEMM body (MFMA bf16) =======================
__device__ __forceinline__ void gemm_body(
    const float* __restrict__ nfeat, const ushort_t* __restrict__ Bt,
    const float* __restrict__ attn_l, const float* __restrict__ attn_r,
    ushort_t* __restrict__ feat, float* __restrict__ el, float* __restrict__ er,
    int blk)
{
    const int w    = threadIdx.x >> 6;
    const int lane = threadIdx.x & 63;
    const int n16  = lane & 15;
    const int quad = lane >> 4;
    const int row0 = blk * 64;

    f32x4 acc[4][4];
    #pragma unroll
    for (int rt = 0; rt < 4; rt++)
        #pragma unroll
        for (int ct = 0; ct < 4; ct++)
            acc[rt][ct] = (f32x4){0.f, 0.f, 0.f, 0.f};

    for (int kb = 0; kb < IN_DIM; kb += 32) {
        short8 a[4], b[4];
        #pragma unroll
        for (int rt = 0; rt < 4; rt++) {
            int r = row0 + rt * 16 + n16;
            r = r < N_NODES ? r : N_NODES - 1;
            const float* p = nfeat + (size_t)r * IN_DIM + kb + quad * 8;
            const float4 v0 = *(const float4*)p;
            const float4 v1 = *(const float4*)(p + 4);
            short8 t;
            t[0] = (short)f2bf(v0.x); t[1] = (short)f2bf(v0.y);
            t[2] = (short)f2bf(v0.z); t[3] = (short)f2bf(v0.w);
            t[4] = (short)f2bf(v1.x); t[5] = (short)f2bf(v1.y);
            t[6] = (short)f2bf(v1.z); t[7] = (short)f2bf(v1.w);
            a[rt] = t;
        }
        #pragma unroll
        for (int ct = 0; ct < 4; ct++) {
            const int c = w * 64 + ct * 16 + n16;
            b[ct] = *(const short8*)(Bt + (size_t)c * 256 + kb + quad * 8);
        }
        #pragma unroll
        for (int rt = 0; rt < 4; rt++)
            #pragma unroll
            for (int ct = 0; ct < 4; ct++)
                acc[rt][ct] = __builtin_amdgcn_mfma_f32_16x16x32_bf16(a[rt], b[ct], acc[rt][ct], 0, 0, 0);
    }

    float alv[4], arv[4];
    #pragma unroll
    for (int ct = 0; ct < 4; ct++) {
        alv[ct] = attn_l[w * 64 + ct * 16 + n16];
        arv[ct] = attn_r[w * 64 + ct * 16 + n16];
    }
    #pragma unroll
    for (int rt = 0; rt < 4; rt++) {
        #pragma unroll
        for (int reg = 0; reg < 4; reg++) {
            const int row = row0 + rt * 16 + quad * 4 + reg;
            const bool ok = row < N_NODES;
            float pl = 0.f, pr = 0.f;
            #pragma unroll
            for (int ct = 0; ct < 4; ct++) {
                const float v = acc[rt][ct][reg];
                if (ok) feat[(size_t)row * HF + w * 64 + ct * 16 + n16] = f2bf(v);
                pl = fmaf(v, alv[ct], pl);
                pr = fmaf(v, arv[ct], pr);
            }
            #pragma unroll
            for (int m = 8; m >= 1; m >>= 1) {
                pl += __shfl_xor(pl, m);
                pr += __shfl_xor(pr, m);
            }
            if (n16 == 0 && ok) {
                el[row * H_HEADS + w] = pl;
                er[row * H_HEADS + w] = pr;
            }
        }
    }
}

// ======================= K2: full GEMM || LDS-histogram rank (NO device atomics) =======================
// khist block (i,j): edges [i*EPB,(i+1)*EPB), nodes [j*NPB,(j+1)*NPB).
// LDS hist packs 2 nodes/int (16-bit fields). LDS atomicAdd old-value = local rank.
__global__ __launch_bounds__(256) void k2_gemm_hist(
    const float* __restrict__ nfeat, const ushort_t* __restrict__ Bt,
    const float* __restrict__ attn_l, const float* __restrict__ attn_r,
    ushort_t* __restrict__ feat, float* __restrict__ el, float* __restrict__ er,
    const int* __restrict__ dst, ushort_t* __restrict__ rank16, ushort_t* __restrict__ cnt16)
{
    __shared__ int hist[NPB / 2];   // 6250 ints = 25KB
    if (blockIdx.x < NBLK_GEMM) {
        gemm_body(nfeat, Bt, attn_l, attn_r, feat, el, er, blockIdx.x);
    } else {
        const int kb = (int)blockIdx.x - NBLK_GEMM;
        const int i = kb & (BE - 1);       // edge partition
        const int j = kb >> 4;             // node partition
        const int tid = threadIdx.x;
        const int ebase = i * EPB;
        const int nbase = j * NPB;

        for (int it = 0; it < (NPB / 2 + 255) / 256; it++) {
            const int li = it * 256 + tid;
            if (li < NPB / 2) hist[li] = 0;
        }
        __syncthreads();

        for (int it = 0; it < (EPB + 255) / 256; it++) {
            const int e = ebase + it * 256 + tid;
            if (e < ebase + EPB) {
                const int d = dst[e];
                if (d >= nbase && d < nbase + NPB) {
                    const int ld = d - nbase;
                    const int old = atomicAdd(&hist[ld >> 1], (ld & 1) ? 65536 : 1);
                    rank16[e] = (ushort_t)((ld & 1) ? (old >> 16) : (old & 0xffff));
                }
            }
        }
        __syncthreads();

        // dump counts: cnt16[i][d] for d in node partition; u32 write covers 2 nodes
        unsigned* out32 = (unsigned*)(cnt16 + (size_t)i * N_NODES + nbase);
        for (int it = 0; it < (NPB / 2 + 255) / 256; it++) {
            const int li = it * 256 + tid;
            if (li < NPB / 2) out32[li] = (unsigned)hist[li];
        }
    }
}

// ======================= K3: per-node prefix over 16 block-counts (in place) + deg ===============
__global__ __launch_bounds__(256) void koff(
    ushort_t* __restrict__ cnt16, int* __restrict__ deg)
{
    const int d = blockIdx.x * 256 + threadIdx.x;
    if (d >= N_NODES) return;
    int sum = 0;
    #pragma unroll
    for (int b = 0; b < BE; b++) {
        const size_t idx = (size_t)b * N_NODES + d;
        const int c = cnt16[idx];
        cnt16[idx] = (ushort_t)sum;   // exclusive within-node prefix
        sum += c;
    }
    deg[d] = sum;
}

// ======================= K4a: per-chunk local scan (196 blocks) =======================
__global__ __launch_bounds__(256) void scanA(
    const int* __restrict__ deg, int* __restrict__ rl, int* __restrict__ bo)
{
    __shared__ int sm[256];
    const int c = blockIdx.x, t = threadIdx.x;
    const int g = c * 256 + t;
    const int v = (g < N_NODES) ? deg[g] : 0;
    sm[t] = v;
    __syncthreads();
    int val = v;
    #pragma unroll
    for (int o = 1; o < 256; o <<= 1) {
        int x = (t >= o) ? sm[t - o] : 0;
        __syncthreads();
        val += x;
        sm[t] = val;
        __syncthreads();
    }
    if (g < N_NODES) rl[g] = val - v;   // exclusive within chunk
    if (t == 255) bo[c] = val;          // chunk total
}

// ======================= K4b: scan chunk sums in place (1 tiny block) =======================
__global__ __launch_bounds__(256) void scanB(int* __restrict__ bo)
{
    __shared__ int sm[256];
    const int t = threadIdx.x;
    const int v = (t < NCHUNK) ? bo[t] : 0;
    sm[t] = v;
    __syncthreads();
    int val = v;
    #pragma unroll
    for (int o = 1; o < 256; o <<= 1) {
        int x = (t >= o) ? sm[t - o] : 0;
        __syncthreads();
        val += x;
        sm[t] = val;
        __syncthreads();
    }
    if (t < NCHUNK) bo[t] = val - v;    // exclusive chunk offsets
}

// ======================= K5: placement — pure streaming, zero atomics =======================
__global__ __launch_bounds__(256) void kplace(
    const int* __restrict__ src, const int* __restrict__ dst, const int* __restrict__ etype,
    const ushort_t* __restrict__ rank16, const ushort_t* __restrict__ cnt16,
    const int* __restrict__ rl, const int* __restrict__ bo, u64* __restrict__ pk)
{
    const int t = blockIdx.x * 256 + threadIdx.x;
    if (t >= E_EDGES / 4) return;
    const int4 s4 = ((const int4*)src)[t];
    const int4 d4 = ((const int4*)dst)[t];
    const int4 e4 = ((const int4*)etype)[t];
    const ushort4 r4 = ((const ushort4*)rank16)[t];
    const int eb = t * 4;
    int ds[4] = {d4.x, d4.y, d4.z, d4.w};
    int ss[4] = {s4.x, s4.y, s4.z, s4.w};
    int ts[4] = {e4.x, e4.y, e4.z, e4.w};
    int rs[4] = {r4.x, r4.y, r4.z, r4.w};
    #pragma unroll
    for (int jj = 0; jj < 4; jj++) {
        const int e = eb + jj;
        const int b = (unsigned)e / EPB;
        const int d = ds[jj];
        const int pos = bo[d >> 8] + rl[d] + (int)cnt16[(size_t)b * N_NODES + d] + rs[jj];
        pk[pos] = (u64)ss[jj] | ((u64)ts[jj] << 16) | ((u64)e << 32);
    }
}

// ======================= agg fallback: any degree (correctness path) =======================
__device__ void agg_fallback(
    int d, int off, int deg, int h, int l,
    const u64* __restrict__ pk, const float* __restrict__ el,
    const float erh, const float* __restrict__ ee,
    const uint2* __restrict__ fb, float* __restrict__ a_out, float* __restrict__ rst)
{
    float m = -INFINITY;
    for (int i = l; i < deg; i += 16) {
        const u64 p = pk[off + i];
        float v = el[(int)(p & 0xffffu) * 4 + h] + erh + ee[(int)((p >> 16) & 0xffu) * 4 + h];
        v = v > 0.f ? v : SLOPE * v;
        m = fmaxf(m, v);
    }
    m = fmaxf(m, __shfl_xor(m, 1));
    m = fmaxf(m, __shfl_xor(m, 2));
    m = fmaxf(m, __shfl_xor(m, 4));
    m = fmaxf(m, __shfl_xor(m, 8));
    float s = 0.f;
    for (int i = l; i < deg; i += 16) {
        const u64 p = pk[off + i];
        float v = el[(int)(p & 0xffffu) * 4 + h] + erh + ee[(int)((p >> 16) & 0xffu) * 4 + h];
        v = v > 0.f ? v : SLOPE * v;
        s += __expf(v - m);
    }
    s += __shfl_xor(s, 1);
    s += __shfl_xor(s, 2);
    s += __shfl_xor(s, 4);
    s += __shfl_xor(s, 8);
    const float inv = 1.f / s;
    for (int i = l; i < deg; i += 16) {
        const u64 p = pk[off + i];
        const int sn = (int)(p & 0xffffu);
        float v = el[sn * 4 + h] + erh + ee[(int)((p >> 16) & 0xffu) * 4 + h];
        v = v > 0.f ? v : SLOPE * v;
        a_out[(int)(p >> 32) * 4 + h] = __expf(v - m) * inv;
    }
    float4 acc = {0.f, 0.f, 0.f, 0.f};
    const int col = h * 16 + l;
    for (int e = 0; e < deg; e++) {
        const u64 p = pk[off + e];
        const int sn = (int)(p & 0xffffu);
        float v = el[sn * 4 + h] + erh + ee[(int)((p >> 16) & 0xffu) * 4 + h];
        v = v > 0.f ? v : SLOPE * v;
        const float aw = __expf(v - m) * inv;
        const uint2 u = fb[(size_t)sn * 64 + col];
        acc.x = fmaf(aw, __uint_as_float(u.x << 16),         acc.x);
        acc.y = fmaf(aw, __uint_as_float(u.x & 0xffff0000u), acc.y);
        acc.z = fmaf(aw, __uint_as_float(u.y << 16),         acc.z);
        acc.w = fmaf(aw, __uint_as_float(u.y & 0xffff0000u), acc.w);
    }
    *(float4*)(rst + (size_t)d * HF + h * 64 + l * 4) = acc;
}

// ======================= K6: wave-per-node softmax + aggregation (v8) =======================
// 64 lanes = 4 head-groups x 16 edge-slots; one node per wave; deg<=64 fast path.
__global__ __launch_bounds__(256) void agg_kernel(
    const u64* __restrict__ pk, const int* __restrict__ rl, const int* __restrict__ bo,
    const int* __restrict__ degarr,
    const float* __restrict__ el, const float* __restrict__ er,
    const float* __restrict__ ee, const ushort_t* __restrict__ feat,
    float* __restrict__ a_out, float* __restrict__ rst)
{
    const int wid  = threadIdx.x >> 6;
    const int lane = threadIdx.x & 63;
    const int h    = lane >> 4;
    const int l    = lane & 15;
    const int d    = blockIdx.x * 4 + wid;   // 12500*4 = 50000 exactly

    __shared__ __align__(16) float    sExp[4][256];   // [wave][edge*4+h], 64 edges
    __shared__ __align__(16) ushort_t sSrc[4][64];

    float* expw = sExp[wid];
    ushort_t* srcw = sSrc[wid];
    const uint2* fb = (const uint2*)feat;

    const int off = bo[d >> 8] + rl[d];
    const int deg = degarr[d];
    const float erh = er[d * 4 + h];

    if (deg <= 64) {
        const int nch = (deg + 15) >> 4;     // <= 4

        // Phase A: leaky scores -> LDS raw; running max
        float m = -INFINITY;
        for (int c = 0; c < nch; c++) {
            const int e = c * 16 + l;
            float v = -INFINITY;
            if (e < deg) {
                const u64 p = pk[off + e];
                const int s  = (int)(p & 0xffffu);
                const int ty = (int)((p >> 16) & 0xffu);
                if (h == 0) srcw[e] = (ushort_t)s;
                v = el[s * 4 + h] + erh + ee[ty * 4 + h];
                v = v > 0.f ? v : SLOPE * v;
                expw[e * 4 + h] = v;
            } else if (h == 0) srcw[e] = 0;  // pad -> row 0, weight 0
            m = fmaxf(m, v);
        }
        m = fmaxf(m, __shfl_xor(m, 1));
        m = fmaxf(m, __shfl_xor(m, 2));
        m = fmaxf(m, __shfl_xor(m, 4));
        m = fmaxf(m, __shfl_xor(m, 8));

        // Phase B: exp in place (pads -> 0), sum
        float s = 0.f;
        for (int c = 0; c < nch; c++) {
            const int e = c * 16 + l;
            float ev = 0.f;
            if (e < deg) ev = __expf(expw[e * 4 + h] - m);
            expw[e * 4 + h] = ev;
            s += ev;
        }
        s += __shfl_xor(s, 1);
        s += __shfl_xor(s, 2);
        s += __shfl_xor(s, 4);
        s += __shfl_xor(s, 8);
        const float inv = (deg > 0) ? 1.f / s : 0.f;

        // wave-level fence: LDS writes above visible to cross-lane reads below
        asm volatile("s_waitcnt lgkmcnt(0)" ::: "memory");

        const float i0 = __shfl(inv, 0),  i1 = __shfl(inv, 16);
        const float i2 = __shfl(inv, 32), i3 = __shfl(inv, 48);

        // Phase C: a_out — head-group h writes chunk h (all 4 groups in parallel)
        if (h < nch) {
            const int e = h * 16 + l;
            if (e < deg) {
                const int eid = (int)(pk[off + e] >> 32);   // L2-hot reload
                const float4 t = *(const float4*)(expw + e * 4);
                float4 av;
                av.x = t.x * i0; av.y = t.y * i1; av.z = t.z * i2; av.w = t.w * i3;
                *(float4*)(a_out + (size_t)eid * 4) = av;
            }
        }

        // Phase D: gather, 8-deep batches
        const int degP = nch << 4;
        const int col = h * 16 + l;
        float4 acc = {0.f, 0.f, 0.f, 0.f};
        for (int e0 = 0; e0 < degP; e0 += 8) {
            uint2 u[8]; float wgt[8];
            #pragma unroll
            for (int jj = 0; jj < 8; jj++) {
                const int e = e0 + jj;
                wgt[jj] = expw[e * 4 + h];
                u[jj] = fb[(size_t)srcw[e] * 64 + col];
            }
            #pragma unroll
            for (int jj = 0; jj < 8; jj++) {
                acc.x = fmaf(wgt[jj], __uint_as_float(u[jj].x << 16),         acc.x);
                acc.y = fmaf(wgt[jj], __uint_as_float(u[jj].x & 0xffff0000u), acc.y);
                acc.z = fmaf(wgt[jj], __uint_as_float(u[jj].y << 16),         acc.z);
                acc.w = fmaf(wgt[jj], __uint_as_float(u[jj].y & 0xffff0000u), acc.w);
            }
        }
        acc.x *= inv; acc.y *= inv; acc.z *= inv; acc.w *= inv;
        *(float4*)(rst + (size_t)d * HF + h * 64 + l * 4) = acc;
    } else {
        agg_fallback(d, off, deg, h, l, pk, el, erh, ee, fb, a_out, rst);
    }
}

extern "C" void kernel_launch(void* const* d_in, const int* in_sizes, int n_in,
                              void* d_out, int out_size, void* d_ws, size_t ws_size,
                              hipStream_t stream) {
    const float* nfeat    = (const float*)d_in[0];
    const float* fc_w     = (const float*)d_in[1];
    const float* fc_e_w   = (const float*)d_in[2];
    const float* attn_l   = (const float*)d_in[3];
    const float* attn_r   = (const float*)d_in[4];
    const float* attn_e   = (const float*)d_in[5];
    const float* edge_emb = (const float*)d_in[6];
    const int*   src      = (const int*)d_in[7];
    const int*   dst      = (const int*)d_in[8];
    const int*   etype    = (const int*)d_in[9];

    float* ws = (float*)d_ws;
    ushort_t* feat = (ushort_t*)(ws + FEATBF_OFF);
    float* el   = ws + EL_OFF;
    float* er   = ws + ER_OFF;
    float* ee   = ws + EE_OFF;
    ushort_t* Bt = (ushort_t*)(ws + BT_OFF);
    int*   ip      = (int*)(ws + INT_OFF);
    ushort_t* cnt16  = (ushort_t*)(ip + CNT_IOFF);
    ushort_t* rank16 = (ushort_t*)(ip + RANK_IOFF);
    int*   deg     = ip + DEG_IOFF;
    int*   rl      = ip + RL_IOFF;
    int*   bo      = ip + BO_IOFF;
    u64*   pk      = (u64*)(ip + PK_IOFF);

    float* rst   = (float*)d_out;                              // [N,H,F]
    float* a_out = (float*)d_out + (size_t)N_NODES * HF;       // [E,H]

    // K1: ee (1 blk) + cast Bt (256) — tiny
    k1_prep<<<257, 256, 0, stream>>>(edge_emb, fc_e_w, attn_e, fc_w, ee, Bt);
    // K2: full GEMM || LDS-histogram rank (no device atomics, no memset needed)
    k2_gemm_hist<<<NBLK_GEMM + NBLK_KHIST, 256, 0, stream>>>(
        nfeat, Bt, attn_l, attn_r, feat, el, er, dst, rank16, cnt16);
    // K3: within-node prefix over the 16 block counts + deg
    koff<<<NCHUNK, 256, 0, stream>>>(cnt16, deg);
    // K4: two-level scan over deg
    scanA<<<NCHUNK, 256, 0, stream>>>(deg, rl, bo);
    scanB<<<1, 256, 0, stream>>>(bo);
    // K5: placement — pure streaming
    kplace<<<NBLK_E4, 256, 0, stream>>>(src, dst, etype, rank16, cnt16, rl, bo, pk);
    // K6: wave-per-node softmax + aggregation
    agg_kernel<<<(N_NODES + 3) / 4, 256, 0, stream>>>(
        pk, rl, bo, deg, el, er, ee, feat, a_out, rst);
}

// Round 6
// 291.804 us; speedup vs baseline: 1.1873x; 1.1873x over previous
//
#include <hip/hip_runtime.h>

#define N_NODES 50000
#define E_EDGES 800000
#define IN_DIM 256
#define H_HEADS 4
#define F_OUT 64
#define EF_DIM 64
#define NT_TYPES 8
#define SLOPE 0.2f
#define HF 256  /* H*F */

typedef __attribute__((ext_vector_type(8))) short short8;
typedef __attribute__((ext_vector_type(4))) float f32x4;
typedef unsigned short ushort_t;
typedef unsigned long long u64;

// workspace layout (float element offsets)
#define FEATBF_OFF 0          /* N*HF bf16 = 6.4M floats */
#define EL_OFF   6400000
#define ER_OFF   6600000
#define EE_OFF   6800000
#define BT_OFF   6800064      /* 256x256 bf16 = 32768 floats */
#define INT_OFF  6832832
// int offsets within int region (identical footprint to R5)
#define CNT_IOFF     0        /* cnt16 ushort[16][50000] = 400,000 ints */
#define RANK_IOFF    400000   /* rank16 ushort[800,000] = 400,000 ints */
#define DEG_IOFF     800000   /* int[50,000] */
#define RL_IOFF      850000   /* int[50,000] */
#define BO_IOFF      900000   /* int[256] */
#define PK_IOFF      900256   /* u64[800,000] (8B aligned: even int offset) */

#define NBLK_GEMM 782         /* ceil(50000/64) */
#define NBLK_E4   782         /* ceil(800000/4/256) */
#define NCHUNK    196         /* ceil(50000/256) */

// hist geometry: 16 edge-slices x 8 node-partitions = 128 blocks
#define BE 16
#define BN 8
#define EPB 50000             /* edges per slice (800000/16) */
#define NPB 6250              /* nodes per partition (50000/8) */
#define NBLK_HIST (BE * BN)   /* 128 */

__device__ __forceinline__ ushort_t f2bf(float f) {
    unsigned u = __float_as_uint(f);
    u += 0x7fffu + ((u >> 16) & 1u);   // round-nearest-even
    return (ushort_t)(u >> 16);
}
__device__ __forceinline__ float bf2f(ushort_t b) {
    return __uint_as_float(((unsigned)b) << 16);
}

// ======================= K1: ee + cast_w (tiny) =======================
__global__ __launch_bounds__(256) void k1_prep(
    const float* __restrict__ edge_emb, const float* __restrict__ fc_e_w,
    const float* __restrict__ attn_e, const float* __restrict__ fc_w,
    float* __restrict__ ee, ushort_t* __restrict__ Bt)
{
    const int b = blockIdx.x;
    if (b == 0) {
        const int c = threadIdx.x;
        const float ae = attn_e[c];
        const int lane = c & 63, h = c >> 6;
        for (int ty = 0; ty < NT_TYPES; ty++) {
            float v = 0.f;
            #pragma unroll 8
            for (int k = 0; k < EF_DIM; k++)
                v = fmaf(edge_emb[ty * EF_DIM + k], fc_e_w[k * (H_HEADS * EF_DIM) + c], v);
            float contrib = v * ae;
            #pragma unroll
            for (int m = 32; m >= 1; m >>= 1) contrib += __shfl_xor(contrib, m);
            if (lane == 0) ee[ty * H_HEADS + h] = contrib;
        }
    } else {
        const int k = b - 1, c = threadIdx.x;
        Bt[(size_t)c * 256 + k] = f2bf(fc_w[(size_t)k * 256 + c]);
    }
}

// ======================= GEMM body (MFMA bf16) =======================
__device__ __forceinline__ void gemm_body(
    const float* __restrict__ nfeat, const ushort_t* __restrict__ Bt,
    const float* __restrict__ attn_l, const float* __restrict__ attn_r,
    ushort_t* __restrict__ feat, float* __restrict__ el, float* __restrict__ er,
    int blk)
{
    const int w    = threadIdx.x >> 6;
    const int lane = threadIdx.x & 63;
    const int n16  = lane & 15;
    const int quad = lane >> 4;
    const int row0 = blk * 64;

    f32x4 acc[4][4];
    #pragma unroll
    for (int rt = 0; rt < 4; rt++)
        #pragma unroll
        for (int ct = 0; ct < 4; ct++)
            acc[rt][ct] = (f32x4){0.f, 0.f, 0.f, 0.f};

    for (int kb = 0; kb < IN_DIM; kb += 32) {
        short8 a[4], b[4];
        #pragma unroll
        for (int rt = 0; rt < 4; rt++) {
            int r = row0 + rt * 16 + n16;
            r = r < N_NODES ? r : N_NODES - 1;
            const float* p = nfeat + (size_t)r * IN_DIM + kb + quad * 8;
            const float4 v0 = *(const float4*)p;
            const float4 v1 = *(const float4*)(p + 4);
            short8 t;
            t[0] = (short)f2bf(v0.x); t[1] = (short)f2bf(v0.y);
            t[2] = (short)f2bf(v0.z); t[3] = (short)f2bf(v0.w);
            t[4] = (short)f2bf(v1.x); t[5] = (short)f2bf(v1.y);
            t[6] = (short)f2bf(v1.z); t[7] = (short)f2bf(v1.w);
            a[rt] = t;
        }
        #pragma unroll
        for (int ct = 0; ct < 4; ct++) {
            const int c = w * 64 + ct * 16 + n16;
            b[ct] = *(const short8*)(Bt + (size_t)c * 256 + kb + quad * 8);
        }
        #pragma unroll
        for (int rt = 0; rt < 4; rt++)
            #pragma unroll
            for (int ct = 0; ct < 4; ct++)
                acc[rt][ct] = __builtin_amdgcn_mfma_f32_16x16x32_bf16(a[rt], b[ct], acc[rt][ct], 0, 0, 0);
    }

    float alv[4], arv[4];
    #pragma unroll
    for (int ct = 0; ct < 4; ct++) {
        alv[ct] = attn_l[w * 64 + ct * 16 + n16];
        arv[ct] = attn_r[w * 64 + ct * 16 + n16];
    }
    #pragma unroll
    for (int rt = 0; rt < 4; rt++) {
        #pragma unroll
        for (int reg = 0; reg < 4; reg++) {
            const int row = row0 + rt * 16 + quad * 4 + reg;
            const bool ok = row < N_NODES;
            float pl = 0.f, pr = 0.f;
            #pragma unroll
            for (int ct = 0; ct < 4; ct++) {
                const float v = acc[rt][ct][reg];
                if (ok) feat[(size_t)row * HF + w * 64 + ct * 16 + n16] = f2bf(v);
                pl = fmaf(v, alv[ct], pl);
                pr = fmaf(v, arv[ct], pr);
            }
            #pragma unroll
            for (int m = 8; m >= 1; m >>= 1) {
                pl += __shfl_xor(pl, m);
                pr += __shfl_xor(pr, m);
            }
            if (n16 == 0 && ok) {
                el[row * H_HEADS + w] = pl;
                er[row * H_HEADS + w] = pr;
            }
        }
    }
}

// ======================= K2: full GEMM || LDS-histogram rank (no device atomics) ==========
// hist block kb: edge slice i = kb&15 ([i*EPB,(i+1)*EPB)), node part j = kb>>4.
// int4 dst loads (4 edges/thread/iter, unroll 2 -> 2 loads in flight).
// LDS hist packs 2 nodes/int; LDS atomicAdd old-value = within-(slice,node) rank.
__global__ __launch_bounds__(256) void k2_gemm_hist(
    const float* __restrict__ nfeat, const ushort_t* __restrict__ Bt,
    const float* __restrict__ attn_l, const float* __restrict__ attn_r,
    ushort_t* __restrict__ feat, float* __restrict__ el, float* __restrict__ er,
    const int* __restrict__ dst, ushort_t* __restrict__ rank16, ushort_t* __restrict__ cnt16)
{
    __shared__ int hist[NPB / 2];   // 3125 ints = 12.5KB (8 blocks/CU still fits)
    if (blockIdx.x < NBLK_GEMM) {
        gemm_body(nfeat, Bt, attn_l, attn_r, feat, el, er, blockIdx.x);
    } else {
        const int kb = (int)blockIdx.x - NBLK_GEMM;
        const int i = kb & (BE - 1);       // edge slice
        const int j = kb >> 4;             // node partition
        const int tid = threadIdx.x;
        const int nbase = j * NPB;

        #pragma unroll
        for (int it = 0; it < (NPB / 2 + 255) / 256; it++) {
            const int li = it * 256 + tid;
            if (li < NPB / 2) hist[li] = 0;
        }
        __syncthreads();

        const int4* dst4 = (const int4*)(dst + i * EPB);
        #pragma unroll 2
        for (int it = 0; it < (EPB / 4 + 255) / 256; it++) {
            const int q = it * 256 + tid;          // int4 index within slice
            if (q < EPB / 4) {
                const int4 d4 = dst4[q];
                const int e = i * EPB + q * 4;
                const int dd[4] = {d4.x, d4.y, d4.z, d4.w};
                #pragma unroll
                for (int u = 0; u < 4; u++) {
                    const int ld = dd[u] - nbase;
                    if ((unsigned)ld < (unsigned)NPB) {
                        const int old = atomicAdd(&hist[ld >> 1], (ld & 1) ? 65536 : 1);
                        rank16[e + u] = (ushort_t)((ld & 1) ? (old >> 16) : (old & 0xffff));
                    }
                }
            }
        }
        __syncthreads();

        // dump counts: cnt16[i][nbase..nbase+NPB); u32 covers 2 nodes
        unsigned* out32 = (unsigned*)(cnt16 + (size_t)i * N_NODES + nbase);
        #pragma unroll
        for (int it = 0; it < (NPB / 2 + 255) / 256; it++) {
            const int li = it * 256 + tid;
            if (li < NPB / 2) out32[li] = (unsigned)hist[li];
        }
    }
}

// ======================= K3: per-node prefix over 16 slice-counts + chunk scan (merged) ====
__global__ __launch_bounds__(256) void k3_off_scan(
    ushort_t* __restrict__ cnt16, int* __restrict__ deg,
    int* __restrict__ rl, int* __restrict__ bo)
{
    __shared__ int sm[256];
    const int c = blockIdx.x, t = threadIdx.x;
    const int d = c * 256 + t;
    int sum = 0;
    if (d < N_NODES) {
        #pragma unroll
        for (int b = 0; b < BE; b++) {
            const size_t idx = (size_t)b * N_NODES + d;
            const int cc = cnt16[idx];
            cnt16[idx] = (ushort_t)sum;   // exclusive within-node prefix
            sum += cc;
        }
        deg[d] = sum;
    }
    sm[t] = sum;
    __syncthreads();
    int val = sum;
    #pragma unroll
    for (int o = 1; o < 256; o <<= 1) {
        int x = (t >= o) ? sm[t - o] : 0;
        __syncthreads();
        val += x;
        sm[t] = val;
        __syncthreads();
    }
    if (d < N_NODES) rl[d] = val - sum;   // exclusive within chunk
    if (t == 255) bo[c] = val;            // chunk total
}

// ======================= K4: scan chunk sums in place (1 tiny block) =======================
__global__ __launch_bounds__(256) void scanB(int* __restrict__ bo)
{
    __shared__ int sm[256];
    const int t = threadIdx.x;
    const int v = (t < NCHUNK) ? bo[t] : 0;
    sm[t] = v;
    __syncthreads();
    int val = v;
    #pragma unroll
    for (int o = 1; o < 256; o <<= 1) {
        int x = (t >= o) ? sm[t - o] : 0;
        __syncthreads();
        val += x;
        sm[t] = val;
        __syncthreads();
    }
    if (t < NCHUNK) bo[t] = val - v;    // exclusive chunk offsets
}

// ======================= K5: placement — pure streaming, zero atomics =======================
__global__ __launch_bounds__(256) void kplace(
    const int* __restrict__ src, const int* __restrict__ dst, const int* __restrict__ etype,
    const ushort_t* __restrict__ rank16, const ushort_t* __restrict__ cnt16,
    const int* __restrict__ rl, const int* __restrict__ bo, u64* __restrict__ pk)
{
    const int t = blockIdx.x * 256 + threadIdx.x;
    if (t >= E_EDGES / 4) return;
    const int4 s4 = ((const int4*)src)[t];
    const int4 d4 = ((const int4*)dst)[t];
    const int4 e4 = ((const int4*)etype)[t];
    const ushort4 r4 = ((const ushort4*)rank16)[t];
    const int eb = t * 4;
    int ds[4] = {d4.x, d4.y, d4.z, d4.w};
    int ss[4] = {s4.x, s4.y, s4.z, s4.w};
    int ts[4] = {e4.x, e4.y, e4.z, e4.w};
    int rs[4] = {r4.x, r4.y, r4.z, r4.w};
    #pragma unroll
    for (int jj = 0; jj < 4; jj++) {
        const int e = eb + jj;
        const int b = (unsigned)e / EPB;
        const int d = ds[jj];
        const int pos = bo[d >> 8] + rl[d] + (int)cnt16[(size_t)b * N_NODES + d] + rs[jj];
        pk[pos] = (u64)ss[jj] | ((u64)ts[jj] << 16) | ((u64)e << 32);
    }
}

// ======================= agg fallback: any degree (correctness path) =======================
__device__ void agg_fallback(
    int d, int off, int deg, int h, int l,
    const u64* __restrict__ pk, const float* __restrict__ el,
    const float erh, const float* __restrict__ ee,
    const uint2* __restrict__ fb, float* __restrict__ a_out, float* __restrict__ rst)
{
    float m = -INFINITY;
    for (int i = l; i < deg; i += 16) {
        const u64 p = pk[off + i];
        float v = el[(int)(p & 0xffffu) * 4 + h] + erh + ee[(int)((p >> 16) & 0xffu) * 4 + h];
        v = v > 0.f ? v : SLOPE * v;
        m = fmaxf(m, v);
    }
    m = fmaxf(m, __shfl_xor(m, 1));
    m = fmaxf(m, __shfl_xor(m, 2));
    m = fmaxf(m, __shfl_xor(m, 4));
    m = fmaxf(m, __shfl_xor(m, 8));
    float s = 0.f;
    for (int i = l; i < deg; i += 16) {
        const u64 p = pk[off + i];
        float v = el[(int)(p & 0xffffu) * 4 + h] + erh + ee[(int)((p >> 16) & 0xffu) * 4 + h];
        v = v > 0.f ? v : SLOPE * v;
        s += __expf(v - m);
    }
    s += __shfl_xor(s, 1);
    s += __shfl_xor(s, 2);
    s += __shfl_xor(s, 4);
    s += __shfl_xor(s, 8);
    const float inv = 1.f / s;
    for (int i = l; i < deg; i += 16) {
        const u64 p = pk[off + i];
        const int sn = (int)(p & 0xffffu);
        float v = el[sn * 4 + h] + erh + ee[(int)((p >> 16) & 0xffu) * 4 + h];
        v = v > 0.f ? v : SLOPE * v;
        a_out[(int)(p >> 32) * 4 + h] = __expf(v - m) * inv;
    }
    float4 acc = {0.f, 0.f, 0.f, 0.f};
    const int col = h * 16 + l;
    for (int e = 0; e < deg; e++) {
        const u64 p = pk[off + e];
        const int sn = (int)(p & 0xffffu);
        float v = el[sn * 4 + h] + erh + ee[(int)((p >> 16) & 0xffu) * 4 + h];
        v = v > 0.f ? v : SLOPE * v;
        const float aw = __expf(v - m) * inv;
        const uint2 u = fb[(size_t)sn * 64 + col];
        acc.x = fmaf(aw, __uint_as_float(u.x << 16),         acc.x);
        acc.y = fmaf(aw, __uint_as_float(u.x & 0xffff0000u), acc.y);
        acc.z = fmaf(aw, __uint_as_float(u.y << 16),         acc.z);
        acc.w = fmaf(aw, __uint_as_float(u.y & 0xffff0000u), acc.w);
    }
    *(float4*)(rst + (size_t)d * HF + h * 64 + l * 4) = acc;
}

// ======================= K6: wave-per-node softmax + aggregation (v8, unchanged) ============
__global__ __launch_bounds__(256) void agg_kernel(
    const u64* __restrict__ pk, const int* __restrict__ rl, const int* __restrict__ bo,
    const int* __restrict__ degarr,
    const float* __restrict__ el, const float* __restrict__ er,
    const float* __restrict__ ee, const ushort_t* __restrict__ feat,
    float* __restrict__ a_out, float* __restrict__ rst)
{
    const int wid  = threadIdx.x >> 6;
    const int lane = threadIdx.x & 63;
    const int h    = lane >> 4;
    const int l    = lane & 15;
    const int d    = blockIdx.x * 4 + wid;   // 12500*4 = 50000 exactly

    __shared__ __align__(16) float    sExp[4][256];   // [wave][edge*4+h], 64 edges
    __shared__ __align__(16) ushort_t sSrc[4][64];

    float* expw = sExp[wid];
    ushort_t* srcw = sSrc[wid];
    const uint2* fb = (const uint2*)feat;

    const int off = bo[d >> 8] + rl[d];
    const int deg = degarr[d];
    const float erh = er[d * 4 + h];

    if (deg <= 64) {
        const int nch = (deg + 15) >> 4;     // <= 4

        // Phase A: leaky scores -> LDS raw; running max
        float m = -INFINITY;
        for (int c = 0; c < nch; c++) {
            const int e = c * 16 + l;
            float v = -INFINITY;
            if (e < deg) {
                const u64 p = pk[off + e];
                const int s  = (int)(p & 0xffffu);
                const int ty = (int)((p >> 16) & 0xffu);
                if (h == 0) srcw[e] = (ushort_t)s;
                v = el[s * 4 + h] + erh + ee[ty * 4 + h];
                v = v > 0.f ? v : SLOPE * v;
                expw[e * 4 + h] = v;
            } else if (h == 0) srcw[e] = 0;  // pad -> row 0, weight 0
            m = fmaxf(m, v);
        }
        m = fmaxf(m, __shfl_xor(m, 1));
        m = fmaxf(m, __shfl_xor(m, 2));
        m = fmaxf(m, __shfl_xor(m, 4));
        m = fmaxf(m, __shfl_xor(m, 8));

        // Phase B: exp in place (pads -> 0), sum
        float s = 0.f;
        for (int c = 0; c < nch; c++) {
            const int e = c * 16 + l;
            float ev = 0.f;
            if (e < deg) ev = __expf(expw[e * 4 + h] - m);
            expw[e * 4 + h] = ev;
            s += ev;
        }
        s += __shfl_xor(s, 1);
        s += __shfl_xor(s, 2);
        s += __shfl_xor(s, 4);
        s += __shfl_xor(s, 8);
        const float inv = (deg > 0) ? 1.f / s : 0.f;

        // wave-level fence: LDS writes above visible to cross-lane reads below
        asm volatile("s_waitcnt lgkmcnt(0)" ::: "memory");

        const float i0 = __shfl(inv, 0),  i1 = __shfl(inv, 16);
        const float i2 = __shfl(inv, 32), i3 = __shfl(inv, 48);

        // Phase C: a_out — head-group h writes chunk h (all 4 groups in parallel)
        if (h < nch) {
            const int e = h * 16 + l;
            if (e < deg) {
                const int eid = (int)(pk[off + e] >> 32);   // L2-hot reload
                const float4 t = *(const float4*)(expw + e * 4);
                float4 av;
                av.x = t.x * i0; av.y = t.y * i1; av.z = t.z * i2; av.w = t.w * i3;
                *(float4*)(a_out + (size_t)eid * 4) = av;
            }
        }

        // Phase D: gather, 8-deep batches
        const int degP = nch << 4;
        const int col = h * 16 + l;
        float4 acc = {0.f, 0.f, 0.f, 0.f};
        for (int e0 = 0; e0 < degP; e0 += 8) {
            uint2 u[8]; float wgt[8];
            #pragma unroll
            for (int jj = 0; jj < 8; jj++) {
                const int e = e0 + jj;
                wgt[jj] = expw[e * 4 + h];
                u[jj] = fb[(size_t)srcw[e] * 64 + col];
            }
            #pragma unroll
            for (int jj = 0; jj < 8; jj++) {
                acc.x = fmaf(wgt[jj], __uint_as_float(u[jj].x << 16),         acc.x);
                acc.y = fmaf(wgt[jj], __uint_as_float(u[jj].x & 0xffff0000u), acc.y);
                acc.z = fmaf(wgt[jj], __uint_as_float(u[jj].y << 16),         acc.z);
                acc.w = fmaf(wgt[jj], __uint_as_float(u[jj].y & 0xffff0000u), acc.w);
            }
        }
        acc.x *= inv; acc.y *= inv; acc.z *= inv; acc.w *= inv;
        *(float4*)(rst + (size_t)d * HF + h * 64 + l * 4) = acc;
    } else {
        agg_fallback(d, off, deg, h, l, pk, el, erh, ee, fb, a_out, rst);
    }
}

extern "C" void kernel_launch(void* const* d_in, const int* in_sizes, int n_in,
                              void* d_out, int out_size, void* d_ws, size_t ws_size,
                              hipStream_t stream) {
    const float* nfeat    = (const float*)d_in[0];
    const float* fc_w     = (const float*)d_in[1];
    const float* fc_e_w   = (const float*)d_in[2];
    const float* attn_l   = (const float*)d_in[3];
    const float* attn_r   = (const float*)d_in[4];
    const float* attn_e   = (const float*)d_in[5];
    const float* edge_emb = (const float*)d_in[6];
    const int*   src      = (const int*)d_in[7];
    const int*   dst      = (const int*)d_in[8];
    const int*   etype    = (const int*)d_in[9];

    float* ws = (float*)d_ws;
    ushort_t* feat = (ushort_t*)(ws + FEATBF_OFF);
    float* el   = ws + EL_OFF;
    float* er   = ws + ER_OFF;
    float* ee   = ws + EE_OFF;
    ushort_t* Bt = (ushort_t*)(ws + BT_OFF);
    int*   ip      = (int*)(ws + INT_OFF);
    ushort_t* cnt16  = (ushort_t*)(ip + CNT_IOFF);
    ushort_t* rank16 = (ushort_t*)(ip + RANK_IOFF);
    int*   deg     = ip + DEG_IOFF;
    int*   rl      = ip + RL_IOFF;
    int*   bo      = ip + BO_IOFF;
    u64*   pk      = (u64*)(ip + PK_IOFF);

    float* rst   = (float*)d_out;                              // [N,H,F]
    float* a_out = (float*)d_out + (size_t)N_NODES * HF;       // [E,H]

    // K1: ee (1 blk) + cast Bt (256) — tiny
    k1_prep<<<257, 256, 0, stream>>>(edge_emb, fc_e_w, attn_e, fc_w, ee, Bt);
    // K2: full GEMM || LDS-histogram rank (128 hist blocks, int4 loads, 12.5KB LDS)
    k2_gemm_hist<<<NBLK_GEMM + NBLK_HIST, 256, 0, stream>>>(
        nfeat, Bt, attn_l, attn_r, feat, el, er, dst, rank16, cnt16);
    // K3: within-node prefix over 16 slice counts + chunk-local scan (merged)
    k3_off_scan<<<NCHUNK, 256, 0, stream>>>(cnt16, deg, rl, bo);
    // K4: chunk-sum scan
    scanB<<<1, 256, 0, stream>>>(bo);
    // K5: placement — pure streaming
    kplace<<<NBLK_E4, 256, 0, stream>>>(src, dst, etype, rank16, cnt16, rl, bo, pk);
    // K6: wave-per-node softmax + aggregation
    agg_kernel<<<(N_NODES + 3) / 4, 256, 0, stream>>>(
        pk, rl, bo, deg, el, er, ee, feat, a_out, rst);
}

// Round 8
// 270.189 us; speedup vs baseline: 1.2822x; 1.0800x over previous
//
#include <hip/hip_runtime.h>

#define N_NODES 50000
#define E_EDGES 800000
#define IN_DIM 256
#define H_HEADS 4
#define F_OUT 64
#define EF_DIM 64
#define NT_TYPES 8
#define SLOPE 0.2f
#define HF 256  /* H*F */

typedef __attribute__((ext_vector_type(8))) short short8;
typedef __attribute__((ext_vector_type(4))) float f32x4;
typedef unsigned short ushort_t;
typedef unsigned char u8;
typedef unsigned long long u64;

// ---------------- geometry ----------------
#define SLICES   64           /* hist slices */
#define Q4S      3125         /* int4 per slice (64*3125 = 200000 exact) */
#define NCHUNK   49           /* 1024-node scan chunks (49*1024 >= 50000) */
#define NBLK_GEMM  196        /* 196 blocks x 4 tiles = 784 >= 782 */
#define NBLK_L1    261        /* 196 gemm + 64 hist + 1 ee */
#define NBLK_PLACE 196        /* 200000 int4 / 1024 */

// ---------------- workspace layout (float element offsets) ----------------
#define FEATBF_OFF 0          /* N*HF bf16 = 6.4M floats */
#define EL_OFF   6400000
#define ER_OFF   6600000
#define EE_OFF   6800000
#define INT_OFF  6832832      /* (byte offset %8 == 0) */
// int offsets within int region
#define CNT_IOFF     0        /* cnt8 u8[64][50000] = 800,000 ints */
#define RANK_IOFF    800000   /* rank8 u8[800,000] = 200,000 ints */
#define DEG_IOFF     1000000  /* int[50,000] */
#define RL_IOFF      1050000  /* int[50,000] */
#define BO_IOFF      1100000  /* int[64] (49 used) */
#define PK_IOFF      1100064  /* u64[800,000] = 1,600,000 ints (even -> 8B aligned) */

__device__ __forceinline__ ushort_t f2bf(float f) {
    unsigned u = __float_as_uint(f);
    u += 0x7fffu + ((u >> 16) & 1u);   // round-nearest-even
    return (ushort_t)(u >> 16);
}
__device__ __forceinline__ float bf2f(ushort_t b) {
    return __uint_as_float(((unsigned)b) << 16);
}

// ---------------- GEMM tile body (256 threads = 4 waves; B cast from fc_w in-register) ----------
__device__ __forceinline__ void gemm_body(
    const float* __restrict__ nfeat, const float* __restrict__ fc_w,
    const float* __restrict__ attn_l, const float* __restrict__ attn_r,
    ushort_t* __restrict__ feat, float* __restrict__ el, float* __restrict__ er,
    int blk, int tid)
{
    const int w    = tid >> 6;
    const int lane = tid & 63;
    const int n16  = lane & 15;
    const int quad = lane >> 4;
    const int row0 = blk * 64;

    f32x4 acc[4][4];
    #pragma unroll
    for (int rt = 0; rt < 4; rt++)
        #pragma unroll
        for (int ct = 0; ct < 4; ct++)
            acc[rt][ct] = (f32x4){0.f, 0.f, 0.f, 0.f};

    for (int kb = 0; kb < IN_DIM; kb += 32) {
        short8 a[4], bfr[4];
        #pragma unroll
        for (int rt = 0; rt < 4; rt++) {
            int r = row0 + rt * 16 + n16;
            r = r < N_NODES ? r : N_NODES - 1;
            const float* p = nfeat + (size_t)r * IN_DIM + kb + quad * 8;
            const float4 v0 = *(const float4*)p;
            const float4 v1 = *(const float4*)(p + 4);
            short8 t;
            t[0] = (short)f2bf(v0.x); t[1] = (short)f2bf(v0.y);
            t[2] = (short)f2bf(v0.z); t[3] = (short)f2bf(v0.w);
            t[4] = (short)f2bf(v1.x); t[5] = (short)f2bf(v1.y);
            t[6] = (short)f2bf(v1.z); t[7] = (short)f2bf(v1.w);
            a[rt] = t;
        }
        #pragma unroll
        for (int ct = 0; ct < 4; ct++) {
            const int col = w * 64 + ct * 16 + n16;
            const float* bp = fc_w + (size_t)(kb + quad * 8) * 256 + col;
            short8 t;
            #pragma unroll
            for (int i = 0; i < 8; i++) t[i] = (short)f2bf(bp[(size_t)i * 256]);
            bfr[ct] = t;
        }
        #pragma unroll
        for (int rt = 0; rt < 4; rt++)
            #pragma unroll
            for (int ct = 0; ct < 4; ct++)
                acc[rt][ct] = __builtin_amdgcn_mfma_f32_16x16x32_bf16(a[rt], bfr[ct], acc[rt][ct], 0, 0, 0);
    }

    float alv[4], arv[4];
    #pragma unroll
    for (int ct = 0; ct < 4; ct++) {
        alv[ct] = attn_l[w * 64 + ct * 16 + n16];
        arv[ct] = attn_r[w * 64 + ct * 16 + n16];
    }
    #pragma unroll
    for (int rt = 0; rt < 4; rt++) {
        #pragma unroll
        for (int reg = 0; reg < 4; reg++) {
            const int row = row0 + rt * 16 + quad * 4 + reg;
            const bool ok = row < N_NODES;
            float pl = 0.f, pr = 0.f;
            #pragma unroll
            for (int ct = 0; ct < 4; ct++) {
                const float v = acc[rt][ct][reg];
                if (ok) feat[(size_t)row * HF + w * 64 + ct * 16 + n16] = f2bf(v);
                pl = fmaf(v, alv[ct], pl);
                pr = fmaf(v, arv[ct], pr);
            }
            #pragma unroll
            for (int m2 = 8; m2 >= 1; m2 >>= 1) {
                pl += __shfl_xor(pl, m2);
                pr += __shfl_xor(pr, m2);
            }
            if (n16 == 0 && ok) {
                el[row * H_HEADS + w] = pl;
                er[row * H_HEADS + w] = pr;
            }
        }
    }
}

// ======================= L1: GEMM (x4 tiles/block) || full-range LDS hist || ee ==============
// hist block: slice s = 12500 edges read ONCE; u8 counters packed 4/int in 50KB LDS;
// LDS atomicAdd old-value -> rank8 (packed 4/u32 store). No device atomics anywhere.
__global__ __launch_bounds__(1024) void k1_gemm_hist_ee(
    const float* __restrict__ nfeat, const float* __restrict__ fc_w,
    const float* __restrict__ fc_e_w, const float* __restrict__ attn_l,
    const float* __restrict__ attn_r, const float* __restrict__ attn_e,
    const float* __restrict__ edge_emb, const int* __restrict__ dst,
    ushort_t* __restrict__ feat, float* __restrict__ el, float* __restrict__ er,
    float* __restrict__ ee, u8* __restrict__ rank8, u8* __restrict__ cnt8)
{
    __shared__ int hist[12500];   // 50,000 u8 counters packed 4/int = 50KB
    const int b = blockIdx.x;
    const int tid = threadIdx.x;

    if (b < NBLK_GEMM) {
        const int g = b * 4 + (tid >> 8);
        if (g < 782)
            gemm_body(nfeat, fc_w, attn_l, attn_r, feat, el, er, g, tid & 255);
    } else if (b < NBLK_GEMM + SLICES) {
        const int s = b - NBLK_GEMM;
        for (int i = tid; i < 12500; i += 1024) hist[i] = 0;
        __syncthreads();
        const int4* dst4 = (const int4*)dst;
        unsigned* rank32 = (unsigned*)rank8;
        #pragma unroll
        for (int it = 0; it < 4; it++) {
            const int lq = it * 1024 + tid;
            if (lq < Q4S) {
                const int q = s * Q4S + lq;
                const int4 d4 = dst4[q];
                const int dd[4] = {d4.x, d4.y, d4.z, d4.w};
                unsigned pr = 0;
                #pragma unroll
                for (int u = 0; u < 4; u++) {
                    const int dn = dd[u];
                    const int sh = 8 * (dn & 3);
                    const unsigned old = (unsigned)atomicAdd(&hist[dn >> 2], 1 << sh);
                    pr |= ((old >> sh) & 0xffu) << (8 * u);
                }
                rank32[q] = pr;    // 4 ranks packed, coalesced u32 store
            }
        }
        __syncthreads();
        unsigned* out32 = (unsigned*)(cnt8 + (size_t)s * N_NODES);
        for (int i = tid; i < 12500; i += 1024) out32[i] = (unsigned)hist[i];
    } else {
        // ee: one block, threads 0-255
        if (tid < 256) {
            const int c = tid;
            const float ae = attn_e[c];
            const int lane = c & 63, h = c >> 6;
            for (int ty = 0; ty < NT_TYPES; ty++) {
                float v = 0.f;
                #pragma unroll 8
                for (int k = 0; k < EF_DIM; k++)
                    v = fmaf(edge_emb[ty * EF_DIM + k], fc_e_w[k * 256 + c], v);
                float contrib = v * ae;
                #pragma unroll
                for (int m2 = 32; m2 >= 1; m2 >>= 1) contrib += __shfl_xor(contrib, m2);
                if (lane == 0) ee[ty * H_HEADS + h] = contrib;
            }
        }
    }
}

// ======================= L2: per-node prefix over 64 slice counts + 1024-chunk scan ==========
__global__ __launch_bounds__(1024) void koff_scan(
    u8* __restrict__ cnt8, int* __restrict__ deg,
    int* __restrict__ rl, int* __restrict__ bo)
{
    __shared__ int sm[1024];
    const int b = blockIdx.x, tid = threadIdx.x;
    const int d = b * 1024 + tid;
    int sum = 0;
    if (d < N_NODES) {
        #pragma unroll 8
        for (int s = 0; s < SLICES; s++) {
            const size_t ix = (size_t)s * N_NODES + d;
            const int c = cnt8[ix];
            cnt8[ix] = (u8)sum;       // exclusive within-node prefix over slices
            sum += c;
        }
        deg[d] = sum;
    }
    sm[tid] = sum;
    __syncthreads();
    int val = sum;
    for (int o = 1; o < 1024; o <<= 1) {
        const int x = (tid >= o) ? sm[tid - o] : 0;
        __syncthreads();
        val += x;
        sm[tid] = val;
        __syncthreads();
    }
    if (d < N_NODES) rl[d] = val - sum;   // exclusive within chunk
    if (tid == 1023) bo[b] = val;         // chunk total
}

// ======================= L3: scan 49 chunk sums (1 tiny block) =======================
__global__ __launch_bounds__(256) void scanB(int* __restrict__ bo)
{
    __shared__ int sm[256];
    const int t = threadIdx.x;
    const int v = (t < NCHUNK) ? bo[t] : 0;
    sm[t] = v;
    __syncthreads();
    int val = v;
    #pragma unroll
    for (int o = 1; o < 256; o <<= 1) {
        const int x = (t >= o) ? sm[t - o] : 0;
        __syncthreads();
        val += x;
        sm[t] = val;
        __syncthreads();
    }
    if (t < NCHUNK) bo[t] = val - v;    // exclusive chunk offsets
}

// ======================= L4: placement — zero atomics, pure streaming =======================
__global__ __launch_bounds__(1024) void kplace(
    const int* __restrict__ src, const int* __restrict__ dst, const int* __restrict__ etype,
    const u8* __restrict__ rank8, const u8* __restrict__ cnt8,
    const int* __restrict__ rl, const int* __restrict__ bo, u64* __restrict__ pk)
{
    const int q = blockIdx.x * 1024 + threadIdx.x;
    if (q >= E_EDGES / 4) return;
    const int4 s4 = ((const int4*)src)[q];
    const int4 d4 = ((const int4*)dst)[q];
    const int4 e4 = ((const int4*)etype)[q];
    const uchar4 r4 = ((const uchar4*)rank8)[q];
    const int s2 = q / Q4S;               // slice (const-div -> magic mul)
    const u8* cb = cnt8 + (size_t)s2 * N_NODES;
    const int eb = q * 4;
    const int ds[4] = {d4.x, d4.y, d4.z, d4.w};
    const int ss[4] = {s4.x, s4.y, s4.z, s4.w};
    const int ts[4] = {e4.x, e4.y, e4.z, e4.w};
    const int rs[4] = {r4.x, r4.y, r4.z, r4.w};
    #pragma unroll
    for (int u = 0; u < 4; u++) {
        const int dn = ds[u];
        const int pos = bo[dn >> 10] + rl[dn] + (int)cb[dn] + rs[u];
        pk[pos] = (u64)ss[u] | ((u64)ts[u] << 16) | ((u64)(eb + u) << 32);
    }
}

// ======================= agg fallback: any degree (correctness path) =======================
__device__ void agg_fallback(
    int d, int off, int dg, int h, int l,
    const u64* __restrict__ pk, const float* __restrict__ el,
    const float erh, const float* __restrict__ ee,
    const uint2* __restrict__ fb, float* __restrict__ a_out, float* __restrict__ rst)
{
    float m = -INFINITY;
    for (int i = l; i < dg; i += 16) {
        const u64 p = pk[off + i];
        float v = el[(int)(p & 0xffffu) * 4 + h] + erh + ee[(int)((p >> 16) & 0xffu) * 4 + h];
        v = v > 0.f ? v : SLOPE * v;
        m = fmaxf(m, v);
    }
    m = fmaxf(m, __shfl_xor(m, 1));
    m = fmaxf(m, __shfl_xor(m, 2));
    m = fmaxf(m, __shfl_xor(m, 4));
    m = fmaxf(m, __shfl_xor(m, 8));
    float s = 0.f;
    for (int i = l; i < dg; i += 16) {
        const u64 p = pk[off + i];
        float v = el[(int)(p & 0xffffu) * 4 + h] + erh + ee[(int)((p >> 16) & 0xffu) * 4 + h];
        v = v > 0.f ? v : SLOPE * v;
        s += __expf(v - m);
    }
    s += __shfl_xor(s, 1);
    s += __shfl_xor(s, 2);
    s += __shfl_xor(s, 4);
    s += __shfl_xor(s, 8);
    const float inv = 1.f / s;
    for (int i = l; i < dg; i += 16) {
        const u64 p = pk[off + i];
        const int sn = (int)(p & 0xffffu);
        float v = el[sn * 4 + h] + erh + ee[(int)((p >> 16) & 0xffu) * 4 + h];
        v = v > 0.f ? v : SLOPE * v;
        a_out[(int)(p >> 32) * 4 + h] = __expf(v - m) * inv;
    }
    float4 acc = {0.f, 0.f, 0.f, 0.f};
    const int col = h * 16 + l;
    for (int e = 0; e < dg; e++) {
        const u64 p = pk[off + e];
        const int sn = (int)(p & 0xffffu);
        float v = el[sn * 4 + h] + erh + ee[(int)((p >> 16) & 0xffu) * 4 + h];
        v = v > 0.f ? v : SLOPE * v;
        const float aw = __expf(v - m) * inv;
        const uint2 u = fb[(size_t)sn * 64 + col];
        acc.x = fmaf(aw, __uint_as_float(u.x << 16),         acc.x);
        acc.y = fmaf(aw, __uint_as_float(u.x & 0xffff0000u), acc.y);
        acc.z = fmaf(aw, __uint_as_float(u.y << 16),         acc.z);
        acc.w = fmaf(aw, __uint_as_float(u.y & 0xffff0000u), acc.w);
    }
    *(float4*)(rst + (size_t)d * HF + h * 64 + l * 4) = acc;
}

// ======================= L5: wave-per-node softmax + aggregation (v8; 1024-chunk rl/bo) ======
__global__ __launch_bounds__(256) void agg_kernel(
    const u64* __restrict__ pk, const int* __restrict__ rl, const int* __restrict__ bo,
    const int* __restrict__ degarr,
    const float* __restrict__ el, const float* __restrict__ er,
    const float* __restrict__ ee, const ushort_t* __restrict__ feat,
    float* __restrict__ a_out, float* __restrict__ rst)
{
    const int wid  = threadIdx.x >> 6;
    const int lane = threadIdx.x & 63;
    const int h    = lane >> 4;
    const int l    = lane & 15;
    const int d    = blockIdx.x * 4 + wid;   // 12500*4 = 50000 exactly

    __shared__ __align__(16) float    sExp[4][256];
    __shared__ __align__(16) ushort_t sSrc[4][64];

    float* expw = sExp[wid];
    ushort_t* srcw = sSrc[wid];
    const uint2* fb = (const uint2*)feat;

    const int off = bo[d >> 10] + rl[d];
    const int dg = degarr[d];
    const float erh = er[d * 4 + h];

    if (dg <= 64) {
        const int nch = (dg + 15) >> 4;     // <= 4

        // Phase A: leaky scores -> LDS raw; running max
        float m = -INFINITY;
        for (int c = 0; c < nch; c++) {
            const int e = c * 16 + l;
            float v = -INFINITY;
            if (e < dg) {
                const u64 p = pk[off + e];
                const int sn = (int)(p & 0xffffu);
                const int ty = (int)((p >> 16) & 0xffu);
                if (h == 0) srcw[e] = (ushort_t)sn;
                v = el[sn * 4 + h] + erh + ee[ty * 4 + h];
                v = v > 0.f ? v : SLOPE * v;
                expw[e * 4 + h] = v;
            } else if (h == 0) srcw[e] = 0;  // pad -> row 0, weight 0
            m = fmaxf(m, v);
        }
        m = fmaxf(m, __shfl_xor(m, 1));
        m = fmaxf(m, __shfl_xor(m, 2));
        m = fmaxf(m, __shfl_xor(m, 4));
        m = fmaxf(m, __shfl_xor(m, 8));

        // Phase B: exp in place (pads -> 0), sum
        float s = 0.f;
        for (int c = 0; c < nch; c++) {
            const int e = c * 16 + l;
            float ev = 0.f;
            if (e < dg) ev = __expf(expw[e * 4 + h] - m);
            expw[e * 4 + h] = ev;
            s += ev;
        }
        s += __shfl_xor(s, 1);
        s += __shfl_xor(s, 2);
        s += __shfl_xor(s, 4);
        s += __shfl_xor(s, 8);
        const float inv = (dg > 0) ? 1.f / s : 0.f;

        // wave-level fence: LDS writes above visible to cross-lane reads below
        asm volatile("s_waitcnt lgkmcnt(0)" ::: "memory");

        const float i0 = __shfl(inv, 0),  i1 = __shfl(inv, 16);
        const float i2 = __shfl(inv, 32), i3 = __shfl(inv, 48);

        // Phase C: a_out — head-group h writes chunk h (all 4 groups in parallel)
        if (h < nch) {
            const int e = h * 16 + l;
            if (e < dg) {
                const int eid = (int)(pk[off + e] >> 32);   // L2-hot reload
                const float4 t = *(const float4*)(expw + e * 4);
                float4 av;
                av.x = t.x * i0; av.y = t.y * i1; av.z = t.z * i2; av.w = t.w * i3;
                *(float4*)(a_out + (size_t)eid * 4) = av;
            }
        }

        // Phase D: gather, 8-deep batches
        const int degP = nch << 4;
        const int col = h * 16 + l;
        float4 acc = {0.f, 0.f, 0.f, 0.f};
        for (int e0 = 0; e0 < degP; e0 += 8) {
            uint2 u[8]; float wgt[8];
            #pragma unroll
            for (int jj = 0; jj < 8; jj++) {
                const int e = e0 + jj;
                wgt[jj] = expw[e * 4 + h];
                u[jj] = fb[(size_t)srcw[e] * 64 + col];
            }
            #pragma unroll
            for (int jj = 0; jj < 8; jj++) {
                acc.x = fmaf(wgt[jj], __uint_as_float(u[jj].x << 16),         acc.x);
                acc.y = fmaf(wgt[jj], __uint_as_float(u[jj].x & 0xffff0000u), acc.y);
                acc.z = fmaf(wgt[jj], __uint_as_float(u[jj].y << 16),         acc.z);
                acc.w = fmaf(wgt[jj], __uint_as_float(u[jj].y & 0xffff0000u), acc.w);
            }
        }
        acc.x *= inv; acc.y *= inv; acc.z *= inv; acc.w *= inv;
        *(float4*)(rst + (size_t)d * HF + h * 64 + l * 4) = acc;
    } else {
        agg_fallback(d, off, dg, h, l, pk, el, erh, ee, fb, a_out, rst);
    }
}

extern "C" void kernel_launch(void* const* d_in, const int* in_sizes, int n_in,
                              void* d_out, int out_size, void* d_ws, size_t ws_size,
                              hipStream_t stream) {
    const float* nfeat    = (const float*)d_in[0];
    const float* fc_w     = (const float*)d_in[1];
    const float* fc_e_w   = (const float*)d_in[2];
    const float* attn_l   = (const float*)d_in[3];
    const float* attn_r   = (const float*)d_in[4];
    const float* attn_e   = (const float*)d_in[5];
    const float* edge_emb = (const float*)d_in[6];
    const int*   src      = (const int*)d_in[7];
    const int*   dst      = (const int*)d_in[8];
    const int*   etype    = (const int*)d_in[9];

    float* ws = (float*)d_ws;
    ushort_t* feat = (ushort_t*)(ws + FEATBF_OFF);
    float* el   = ws + EL_OFF;
    float* er   = ws + ER_OFF;
    float* ee   = ws + EE_OFF;
    int*   ip      = (int*)(ws + INT_OFF);
    u8*    cnt8    = (u8*)(ip + CNT_IOFF);
    u8*    rank8   = (u8*)(ip + RANK_IOFF);
    int*   deg     = ip + DEG_IOFF;
    int*   rl      = ip + RL_IOFF;
    int*   bo      = ip + BO_IOFF;
    u64*   pk      = (u64*)(ip + PK_IOFF);

    float* rst   = (float*)d_out;                              // [N,H,F]
    float* a_out = (float*)d_out + (size_t)N_NODES * HF;       // [E,H]

    // L1: GEMM (782 tiles, B cast in-register) || 64 full-range LDS hist slices || ee
    k1_gemm_hist_ee<<<NBLK_L1, 1024, 0, stream>>>(
        nfeat, fc_w, fc_e_w, attn_l, attn_r, attn_e, edge_emb, dst,
        feat, el, er, ee, rank8, cnt8);
    // L2: per-node prefix over slice counts + chunk-local scan
    koff_scan<<<NCHUNK, 1024, 0, stream>>>(cnt8, deg, rl, bo);
    // L3: chunk-sum scan
    scanB<<<1, 256, 0, stream>>>(bo);
    // L4: placement — zero atomics
    kplace<<<NBLK_PLACE, 1024, 0, stream>>>(src, dst, etype, rank8, cnt8, rl, bo, pk);
    // L5: wave-per-node softmax + aggregation
    agg_kernel<<<(N_NODES + 3) / 4, 256, 0, stream>>>(
        pk, rl, bo, deg, el, er, ee, feat, a_out, rst);
}